// Round 1
// baseline (828.494 us; speedup 1.0000x reference)
//
#include <hip/hip_runtime.h>

// Problem constants (from reference)
constexpr int N_FRAMES   = 2000;
constexpr int BATCH      = 32;
constexpr int TARGET_LEN = 1000;
constexpr int VOCAB      = 256;
#define NEG (-1e30f)

// One block per batch item. Thread j owns DP column j.
// alpha row kept in LDS, double buffered; one barrier per row.
__global__ __launch_bounds__(1024)
void align_dp_kernel(const float* __restrict__ scores,   // [N, B, V]
                     const int*   __restrict__ targets,  // [B, T]
                     const int*   __restrict__ in_len,   // [B]
                     const int*   __restrict__ tg_len,   // [B]
                     float*       __restrict__ ws_final) // [B]
{
    const int b   = blockIdx.x;
    const int tid = threadIdx.x;

    __shared__ float abuf[2][TARGET_LEN];

    const int inlen = in_len[b];
    const int tlen  = tg_len[b];

    const bool active = (tid < TARGET_LEN);
    int tok = 0;
    if (active) tok = targets[b * TARGET_LEN + tid];

    // Column gather pointer: scores[i, b, tok] = scores + i*B*V + b*V + tok
    const float* col = scores + (size_t)b * VOCAB + tok;
    const size_t rstride = (size_t)BATCH * VOCAB;

    // ---- row 0 ----
    float a0 = NEG;
    if (active) {
        float e0 = col[0];
        a0 = (tid == 0) ? e0 : NEG;
        abuf[0][tid] = a0;
        if (inlen == 1 && tid == tlen - 1) ws_final[b] = a0;  // safety (inlen>=1000 in practice)
    }

    // ---- rows 1..N-1, with 1-row emit prefetch ----
    float e_cur = 0.0f, e_nxt = 0.0f;
    if (active) e_cur = col[rstride];  // row 1
    int p = 0;
    for (int i = 1; i < N_FRAMES; ++i) {
        if (active && (i + 1) < N_FRAMES) {
            e_nxt = col[(size_t)(i + 1) * rstride];   // issue early; consumed next iter
        }
        __syncthreads();   // row i-1 (buf p) fully written; also orders buf reuse
        if (active) {
            float ai = abuf[p][tid];
            float al = (tid > 0) ? abuf[p][tid - 1] : NEG;
            // logaddexp(al, ai)
            float m = fmaxf(ai, al);
            float d = fminf(ai, al) - m;          // <= 0
            float v = e_cur + m + __logf(1.0f + __expf(d));
            abuf[p ^ 1][tid] = v;
            if (i == inlen - 1 && tid == tlen - 1) ws_final[b] = v;
        }
        p ^= 1;
        e_cur = e_nxt;
    }
}

// Final scalar: out = -sum(ws_final)/BATCH. Unconditional write -> deterministic
// across graph replays regardless of buffer poisoning.
__global__ void reduce_kernel(const float* __restrict__ ws_final, float* __restrict__ out)
{
    if (threadIdx.x == 0 && blockIdx.x == 0) {
        float s = 0.0f;
        for (int b = 0; b < BATCH; ++b) s += ws_final[b];
        out[0] = -s / (float)BATCH;
    }
}

extern "C" void kernel_launch(void* const* d_in, const int* in_sizes, int n_in,
                              void* d_out, int out_size, void* d_ws, size_t ws_size,
                              hipStream_t stream)
{
    const float* scores  = (const float*)d_in[0];
    const int*   targets = (const int*)  d_in[1];
    const int*   in_len  = (const int*)  d_in[2];
    const int*   tg_len  = (const int*)  d_in[3];
    float*       out     = (float*)d_out;
    float*       ws      = (float*)d_ws;   // BATCH floats of scratch

    align_dp_kernel<<<BATCH, 1024, 0, stream>>>(scores, targets, in_len, tg_len, ws);
    reduce_kernel<<<1, 64, 0, stream>>>(ws, out);
}